// Round 5
// baseline (147.359 us; speedup 1.0000x reference)
//
#include <hip/hip_runtime.h>
#include <hip/hip_bf16.h>
#include <math.h>

// Problem constants: B=32, L=688, M=4, C=32
#define BB 32
#define LL 688
#define MM 4
#define CC 32
#define ROWS (BB * LL)        // 22016
#define RPW 4                 // rows per wave
#define WPB 4                 // waves per block (256 threads)
#define RPB (RPW * WPB)       // 16 rows per block
#define NBLK (ROWS / RPB)     // 1376 blocks
#define COUNTER_OFF 65536     // byte offset of ticket counter in d_ws

struct Partial { float v[8]; };   // {cls, ptr, cnt, bce, vm, pad...} 32 B

__device__ __forceinline__ float max12(float4 x, float4 y, float4 z) {
    return fmaxf(fmaxf(fmaxf(fmaxf(x.x, x.y), fmaxf(x.z, x.w)),
                       fmaxf(fmaxf(y.x, y.y), fmaxf(y.z, y.w))),
                 fmaxf(fmaxf(z.x, z.y), fmaxf(z.z, z.w)));
}

__device__ __forceinline__ float msum12(float4 x, float4 y, float4 z,
                                        float4 f0, float4 f1, float4 f2, float m) {
    float s = 0.f;
    s = fmaf(f0.x, __expf(x.x - m), s);
    s = fmaf(f0.y, __expf(x.y - m), s);
    s = fmaf(f0.z, __expf(x.z - m), s);
    s = fmaf(f0.w, __expf(x.w - m), s);
    s = fmaf(f1.x, __expf(y.x - m), s);
    s = fmaf(f1.y, __expf(y.y - m), s);
    s = fmaf(f1.z, __expf(y.z - m), s);
    s = fmaf(f1.w, __expf(y.w - m), s);
    s = fmaf(f2.x, __expf(z.x - m), s);
    s = fmaf(f2.y, __expf(z.y - m), s);
    s = fmaf(f2.z, __expf(z.z - m), s);
    s = fmaf(f2.w, __expf(z.w - m), s);
    return s;
}

// One wave64 per 4 consecutive rows. All independent loads issued up front so
// gather-chain latency hides under the shuffle reductions. Block writes one
// partial (agent-scope stores); last block (ticket) reduces all partials.
__global__ __launch_bounds__(256) void fused_kernel(
    const float* __restrict__ tag_logits,
    const float* __restrict__ pl,
    const float* __restrict__ epl,
    const int* __restrict__ tag_targets,
    const int* __restrict__ box,
    const int* __restrict__ dtm,
    const int* __restrict__ am,
    Partial* __restrict__ partials,
    unsigned int* __restrict__ counter,
    float* __restrict__ out)
{
    __shared__ float red[WPB][5];
    __shared__ int lastflag;
    const int wave = threadIdx.x >> 6;
    const int lane = threadIdx.x & 63;
    const int row0 = blockIdx.x * RPB + wave * RPW;
    const int bat  = row0 / LL;
    const int jcol0 = row0 - bat * LL;

    const int* mrow = dtm + bat * (2 * LL) + LL;   // seq_mask[bat, :]
    const int4* maskp = (const int4*)mrow;
    const bool has2 = (lane < 44);                 // 172 - 128

    // ---- issue ALL independent loads up front ----
    const int4 mi0 = maskp[lane];
    const int4 mi1 = maskp[lane + 64];
    const int4 mi2 = has2 ? maskp[lane + 128] : make_int4(0, 0, 0, 0);

    const float4 NEGV = make_float4(-INFINITY, -INFINITY, -INFINITY, -INFINITY);
    const float4* rp0 = (const float4*)(pl + (size_t)(row0 + 0) * LL);
    const float4* rp1 = (const float4*)(pl + (size_t)(row0 + 1) * LL);
    const float4* rp2 = (const float4*)(pl + (size_t)(row0 + 2) * LL);
    const float4* rp3 = (const float4*)(pl + (size_t)(row0 + 3) * LL);
    const float4 a0 = rp0[lane], a1 = rp0[lane + 64], a2 = has2 ? rp0[lane + 128] : NEGV;
    const float4 c0 = rp1[lane], c1 = rp1[lane + 64], c2 = has2 ? rp1[lane + 128] : NEGV;
    const float4 d0 = rp2[lane], d1 = rp2[lane + 64], d2 = has2 ? rp2[lane + 128] : NEGV;
    const float4 e0 = rp3[lane], e1 = rp3[lane + 64], e2 = has2 ? rp3[lane + 128] : NEGV;

    // tail gather chain (lanes 0-15 only): box -> mask -> logit
    const int r  = (lane & 15) >> 2;
    const int mi = lane & 3;
    const int rowr = row0 + r;
    int t = -1, tmask = 0;
    float xj = 0.f;
    if (lane < 16) {
        t = box[(size_t)rowr * MM + mi];
        const int tcl = t < 0 ? 0 : (t > LL - 1 ? LL - 1 : t);
        tmask = mrow[tcl];
        xj = pl[(size_t)rowr * LL + tcl];
    }

    // cls loads (both passes)
    const int half = lane >> 5;
    const int cid  = lane & 31;
    const float clsx0 = tag_logits[(size_t)(row0 + half) * CC + cid];
    const float clsx1 = tag_logits[(size_t)(row0 + 2 + half) * CC + cid];
    const int tg0 = tag_targets[row0 + half];
    const int tg1 = tag_targets[row0 + 2 + half];

    // bce loads (lanes 0-3)
    int seq2 = 0, data2 = 0;
    float xe = 0.f;
    if (lane < 4) {
        const int offb = bat * (2 * LL) + LL + (jcol0 + lane);
        seq2  = am[offb];
        data2 = dtm[offb];
        xe    = epl[row0 + lane];
    }

    // ---- mask -> float ----
    const float4 f0 = make_float4(mi0.x ? 1.f : 0.f, mi0.y ? 1.f : 0.f,
                                  mi0.z ? 1.f : 0.f, mi0.w ? 1.f : 0.f);
    const float4 f1 = make_float4(mi1.x ? 1.f : 0.f, mi1.y ? 1.f : 0.f,
                                  mi1.z ? 1.f : 0.f, mi1.w ? 1.f : 0.f);
    const float4 f2 = make_float4(mi2.x ? 1.f : 0.f, mi2.y ? 1.f : 0.f,
                                  mi2.z ? 1.f : 0.f, mi2.w ? 1.f : 0.f);

    // ---- 4 interleaved wave reductions: max then masked exp-sum ----
    float pm0 = max12(a0, a1, a2);
    float pm1 = max12(c0, c1, c2);
    float pm2 = max12(d0, d1, d2);
    float pm3 = max12(e0, e1, e2);
    #pragma unroll
    for (int off = 32; off >= 1; off >>= 1) {
        pm0 = fmaxf(pm0, __shfl_xor(pm0, off));
        pm1 = fmaxf(pm1, __shfl_xor(pm1, off));
        pm2 = fmaxf(pm2, __shfl_xor(pm2, off));
        pm3 = fmaxf(pm3, __shfl_xor(pm3, off));
    }
    float ps0 = msum12(a0, a1, a2, f0, f1, f2, pm0);
    float ps1 = msum12(c0, c1, c2, f0, f1, f2, pm1);
    float ps2 = msum12(d0, d1, d2, f0, f1, f2, pm2);
    float ps3 = msum12(e0, e1, e2, f0, f1, f2, pm3);
    #pragma unroll
    for (int off = 32; off >= 1; off >>= 1) {
        ps0 += __shfl_xor(ps0, off);
        ps1 += __shfl_xor(ps1, off);
        ps2 += __shfl_xor(ps2, off);
        ps3 += __shfl_xor(ps3, off);
    }

    // ---- pointer tail: dedupe + loss on lanes 0-15 ----
    const int ta  = __shfl(t, (lane & ~3));
    const int tb  = __shfl(t, (lane & ~3) + 1);
    const int tc2 = __shfl(t, (lane & ~3) + 2);
    float contrib = 0.f, ccnt = 0.f;
    if (lane < 16) {
        const bool dup = (mi > 0 && t == ta) || (mi > 1 && t == tb) || (mi > 2 && t == tc2);
        if (t >= 0 && !dup && tmask) {
            const float mxr = (r == 0) ? pm0 : (r == 1) ? pm1 : (r == 2) ? pm2 : pm3;
            const float dnr = ((r == 0) ? ps0 : (r == 1) ? ps1 : (r == 2) ? ps2 : ps3) + 1e-10f;
            const float p = __expf(xj - mxr) / dnr + 1e-10f;
            const float v = -__logf(p);
            contrib = v;
            ccnt = (v != 0.0f) ? 1.f : 0.f;
        }
    }
    contrib += __shfl_xor(contrib, 1); contrib += __shfl_xor(contrib, 2);
    ccnt    += __shfl_xor(ccnt, 1);    ccnt    += __shfl_xor(ccnt, 2);
    const float ptr_sum = __shfl(contrib, 0) + __shfl(contrib, 4) +
                          __shfl(contrib, 8) + __shfl(contrib, 12);
    const float ptr_cnt = __shfl(ccnt, 0) + __shfl(ccnt, 4) +
                          __shfl(ccnt, 8) + __shfl(ccnt, 12);

    // ---- cls: 2 passes, half-wave per row ----
    float cls_tot = 0.f;
    {
        float cm = clsx0;
        #pragma unroll
        for (int off = 16; off >= 1; off >>= 1)
            cm = fmaxf(cm, __shfl_xor(cm, off, 32));
        float cs = __expf(clsx0 - cm);
        #pragma unroll
        for (int off = 16; off >= 1; off >>= 1)
            cs += __shfl_xor(cs, off, 32);
        const float xt = __shfl(clsx0, tg0 + (lane & 32));
        const float c = (cm + __logf(cs)) - xt;
        cls_tot += __shfl(c, 0) + __shfl(c, 32);
    }
    {
        float cm = clsx1;
        #pragma unroll
        for (int off = 16; off >= 1; off >>= 1)
            cm = fmaxf(cm, __shfl_xor(cm, off, 32));
        float cs = __expf(clsx1 - cm);
        #pragma unroll
        for (int off = 16; off >= 1; off >>= 1)
            cs += __shfl_xor(cs, off, 32);
        const float xt = __shfl(clsx1, tg1 + (lane & 32));
        const float c = (cm + __logf(cs)) - xt;
        cls_tot += __shfl(c, 0) + __shfl(c, 32);
    }

    // ---- bce on lanes 0-3 ----
    float bsum = 0.f, vsum = 0.f;
    if (lane < 4 && seq2) {
        const float te = (!data2) ? 1.f : 0.f;
        bsum = fmaxf(xe, 0.f) - xe * te + log1pf(__expf(-fabsf(xe)));
        vsum = 1.f;
    }
    bsum += __shfl_xor(bsum, 1); bsum += __shfl_xor(bsum, 2);
    vsum += __shfl_xor(vsum, 1); vsum += __shfl_xor(vsum, 2);

    if (lane == 0) {
        red[wave][0] = cls_tot;
        red[wave][1] = ptr_sum;
        red[wave][2] = ptr_cnt;
        red[wave][3] = bsum;
        red[wave][4] = vsum;
    }
    __syncthreads();
    if (threadIdx.x == 0) {
        float p0 = red[0][0] + red[1][0] + red[2][0] + red[3][0];
        float p1 = red[0][1] + red[1][1] + red[2][1] + red[3][1];
        float p2 = red[0][2] + red[1][2] + red[2][2] + red[3][2];
        float p3 = red[0][3] + red[1][3] + red[2][3] + red[3][3];
        float p4 = red[0][4] + red[1][4] + red[2][4] + red[3][4];
        float* q = partials[blockIdx.x].v;
        __hip_atomic_store(q + 0, p0, __ATOMIC_RELAXED, __HIP_MEMORY_SCOPE_AGENT);
        __hip_atomic_store(q + 1, p1, __ATOMIC_RELAXED, __HIP_MEMORY_SCOPE_AGENT);
        __hip_atomic_store(q + 2, p2, __ATOMIC_RELAXED, __HIP_MEMORY_SCOPE_AGENT);
        __hip_atomic_store(q + 3, p3, __ATOMIC_RELAXED, __HIP_MEMORY_SCOPE_AGENT);
        __hip_atomic_store(q + 4, p4, __ATOMIC_RELAXED, __HIP_MEMORY_SCOPE_AGENT);
        __threadfence();
        const unsigned old = atomicAdd(counter, 1u);
        lastflag = (old == NBLK - 1) ? 1 : 0;
    }
    __syncthreads();

    // ---- last block reduces all partials ----
    if (lastflag) {
        __threadfence();
        float c = 0.f, p = 0.f, n = 0.f, e = 0.f, v = 0.f;
        for (int i = threadIdx.x; i < NBLK; i += 256) {
            const float* q = partials[i].v;
            c += __hip_atomic_load(q + 0, __ATOMIC_RELAXED, __HIP_MEMORY_SCOPE_AGENT);
            p += __hip_atomic_load(q + 1, __ATOMIC_RELAXED, __HIP_MEMORY_SCOPE_AGENT);
            n += __hip_atomic_load(q + 2, __ATOMIC_RELAXED, __HIP_MEMORY_SCOPE_AGENT);
            e += __hip_atomic_load(q + 3, __ATOMIC_RELAXED, __HIP_MEMORY_SCOPE_AGENT);
            v += __hip_atomic_load(q + 4, __ATOMIC_RELAXED, __HIP_MEMORY_SCOPE_AGENT);
        }
        #pragma unroll
        for (int off = 32; off >= 1; off >>= 1) {
            c += __shfl_xor(c, off);
            p += __shfl_xor(p, off);
            n += __shfl_xor(n, off);
            e += __shfl_xor(e, off);
            v += __shfl_xor(v, off);
        }
        if (lane == 0) {
            red[wave][0] = c; red[wave][1] = p; red[wave][2] = n;
            red[wave][3] = e; red[wave][4] = v;
        }
        __syncthreads();
        if (threadIdx.x == 0) {
            float tc = 0.f, tp = 0.f, tn = 0.f, tb = 0.f, tv = 0.f;
            #pragma unroll
            for (int i = 0; i < WPB; ++i) {
                tc += red[i][0]; tp += red[i][1]; tn += red[i][2];
                tb += red[i][3]; tv += red[i][4];
            }
            const float cls_loss = tc / (float)ROWS;
            const float ptr_loss = (tn == 0.f) ? 0.f : tp / fmaxf(tn, 1.f);
            const float emp_loss = tb / fmaxf(tv, 1.f);
            out[0] = cls_loss + ptr_loss + emp_loss;
            out[1] = cls_loss;
            out[2] = ptr_loss;
            out[3] = emp_loss;
        }
    }
}

extern "C" void kernel_launch(void* const* d_in, const int* in_sizes, int n_in,
                              void* d_out, int out_size, void* d_ws, size_t ws_size,
                              hipStream_t stream) {
    const float* tag_logits           = (const float*)d_in[0];
    const float* pointer_logits       = (const float*)d_in[1];
    const float* empty_pointer_logits = (const float*)d_in[2];
    const int*   tag_targets          = (const int*)d_in[3];
    const int*   box_indices          = (const int*)d_in[4];
    const int*   data_tag_mask        = (const int*)d_in[5];
    const int*   attention_mask       = (const int*)d_in[6];
    float* out = (float*)d_out;
    Partial* partials = (Partial*)d_ws;
    unsigned int* counter = (unsigned int*)((char*)d_ws + COUNTER_OFF);

    hipMemsetAsync(counter, 0, sizeof(unsigned int), stream);
    fused_kernel<<<NBLK, 256, 0, stream>>>(tag_logits, pointer_logits,
                                           empty_pointer_logits, tag_targets,
                                           box_indices, data_tag_mask,
                                           attention_mask, partials, counter, out);
}

// Round 6
// 113.983 us; speedup vs baseline: 1.2928x; 1.2928x over previous
//
#include <hip/hip_runtime.h>
#include <hip/hip_bf16.h>
#include <math.h>

// Problem constants: B=32, L=688, M=4, C=32
#define BB 32
#define LL 688
#define MM 4
#define CC 32
#define ROWS (BB * LL)        // 22016
#define RPW 2                 // rows per wave
#define NPART (ROWS / RPW)    // 11008 waves = blocks

struct Partial { float v[8]; };   // {cls, ptr, cnt, bce, vm, pad...} 32 B

__device__ __forceinline__ float max12(float4 x, float4 y, float4 z) {
    return fmaxf(fmaxf(fmaxf(fmaxf(x.x, x.y), fmaxf(x.z, x.w)),
                       fmaxf(fmaxf(y.x, y.y), fmaxf(y.z, y.w))),
                 fmaxf(fmaxf(z.x, z.y), fmaxf(z.z, z.w)));
}

__device__ __forceinline__ float msum12(float4 x, float4 y, float4 z,
                                        float4 f0, float4 f1, float4 f2, float m) {
    float s = 0.f;
    s = fmaf(f0.x, __expf(x.x - m), s);
    s = fmaf(f0.y, __expf(x.y - m), s);
    s = fmaf(f0.z, __expf(x.z - m), s);
    s = fmaf(f0.w, __expf(x.w - m), s);
    s = fmaf(f1.x, __expf(y.x - m), s);
    s = fmaf(f1.y, __expf(y.y - m), s);
    s = fmaf(f1.z, __expf(y.z - m), s);
    s = fmaf(f1.w, __expf(y.w - m), s);
    s = fmaf(f2.x, __expf(z.x - m), s);
    s = fmaf(f2.y, __expf(z.y - m), s);
    s = fmaf(f2.z, __expf(z.z - m), s);
    s = fmaf(f2.w, __expf(z.w - m), s);
    return s;
}

// One wave64 per 2 consecutive rows (688%2==0 -> same batch). Fully
// independent 64-thread blocks: no LDS, no syncthreads, no atomics.
// All loads hoisted; 2 interleaved butterfly chains; 8-lane gather tail.
__global__ __launch_bounds__(64) void fused_kernel(
    const float* __restrict__ tag_logits,
    const float* __restrict__ pl,
    const float* __restrict__ epl,
    const int* __restrict__ tag_targets,
    const int* __restrict__ box,
    const int* __restrict__ dtm,
    const int* __restrict__ am,
    Partial* __restrict__ partials)
{
    const int lane = threadIdx.x;
    const int row0 = blockIdx.x * RPW;
    const int bat  = row0 / LL;
    const int jcol0 = row0 - bat * LL;

    const int* mrow = dtm + bat * (2 * LL) + LL;   // seq_mask[bat, :]
    const int4* maskp = (const int4*)mrow;
    const bool has2 = (lane < 44);                 // 172 - 128

    // ---- issue ALL independent loads up front ----
    const int4 mi0 = maskp[lane];
    const int4 mi1 = maskp[lane + 64];
    const int4 mi2 = has2 ? maskp[lane + 128] : make_int4(0, 0, 0, 0);

    const float4 NEGV = make_float4(-INFINITY, -INFINITY, -INFINITY, -INFINITY);
    const float4* rp0 = (const float4*)(pl + (size_t)(row0 + 0) * LL);
    const float4* rp1 = (const float4*)(pl + (size_t)(row0 + 1) * LL);
    const float4 a0 = rp0[lane], a1 = rp0[lane + 64], a2 = has2 ? rp0[lane + 128] : NEGV;
    const float4 c0 = rp1[lane], c1 = rp1[lane + 64], c2 = has2 ? rp1[lane + 128] : NEGV;

    // gather chain (lanes 0-7): box -> mask -> logit
    const int r  = (lane & 7) >> 2;      // row within pair
    const int mi = lane & 3;             // box slot
    const int rowr = row0 + r;
    int t = -1, tmask = 0;
    float xj = 0.f;
    if (lane < 8) {
        t = box[(size_t)rowr * MM + mi];
        const int tcl = t < 0 ? 0 : (t > LL - 1 ? LL - 1 : t);
        tmask = mrow[tcl];
        xj = pl[(size_t)rowr * LL + tcl];
    }

    // cls loads: half-wave per row
    const int half = lane >> 5;
    const int cid  = lane & 31;
    const float clsx = tag_logits[(size_t)(row0 + half) * CC + cid];
    const int   tg   = tag_targets[row0 + half];

    // bce loads (lanes 0-1)
    int seq2 = 0, data2 = 0;
    float xe = 0.f;
    if (lane < 2) {
        const int offb = bat * (2 * LL) + LL + (jcol0 + lane);
        seq2  = am[offb];
        data2 = dtm[offb];
        xe    = epl[row0 + lane];
    }

    // ---- mask -> float ----
    const float4 f0 = make_float4(mi0.x ? 1.f : 0.f, mi0.y ? 1.f : 0.f,
                                  mi0.z ? 1.f : 0.f, mi0.w ? 1.f : 0.f);
    const float4 f1 = make_float4(mi1.x ? 1.f : 0.f, mi1.y ? 1.f : 0.f,
                                  mi1.z ? 1.f : 0.f, mi1.w ? 1.f : 0.f);
    const float4 f2 = make_float4(mi2.x ? 1.f : 0.f, mi2.y ? 1.f : 0.f,
                                  mi2.z ? 1.f : 0.f, mi2.w ? 1.f : 0.f);

    // ---- 2 interleaved wave reductions: max then masked exp-sum ----
    float pm0 = max12(a0, a1, a2);
    float pm1 = max12(c0, c1, c2);
    #pragma unroll
    for (int off = 32; off >= 1; off >>= 1) {
        pm0 = fmaxf(pm0, __shfl_xor(pm0, off));
        pm1 = fmaxf(pm1, __shfl_xor(pm1, off));
    }
    float ps0 = msum12(a0, a1, a2, f0, f1, f2, pm0);
    float ps1 = msum12(c0, c1, c2, f0, f1, f2, pm1);
    #pragma unroll
    for (int off = 32; off >= 1; off >>= 1) {
        ps0 += __shfl_xor(ps0, off);
        ps1 += __shfl_xor(ps1, off);
    }

    // ---- pointer tail: dedupe + loss on lanes 0-7 ----
    const int ta  = __shfl(t, (lane & ~3));
    const int tb  = __shfl(t, (lane & ~3) + 1);
    const int tc2 = __shfl(t, (lane & ~3) + 2);
    float contrib = 0.f, ccnt = 0.f;
    if (lane < 8) {
        const bool dup = (mi > 0 && t == ta) || (mi > 1 && t == tb) || (mi > 2 && t == tc2);
        if (t >= 0 && !dup && tmask) {
            const float mxr = (r == 0) ? pm0 : pm1;
            const float dnr = ((r == 0) ? ps0 : ps1) + 1e-10f;
            const float p = __expf(xj - mxr) / dnr + 1e-10f;
            const float v = -__logf(p);
            contrib = v;
            ccnt = (v != 0.0f) ? 1.f : 0.f;
        }
    }
    contrib += __shfl_xor(contrib, 1); contrib += __shfl_xor(contrib, 2);
    ccnt    += __shfl_xor(ccnt, 1);    ccnt    += __shfl_xor(ccnt, 2);
    const float ptr_sum = __shfl(contrib, 0) + __shfl(contrib, 4);
    const float ptr_cnt = __shfl(ccnt, 0) + __shfl(ccnt, 4);

    // ---- cls: one pass, half-wave per row ----
    float cm = clsx;
    #pragma unroll
    for (int off = 16; off >= 1; off >>= 1)
        cm = fmaxf(cm, __shfl_xor(cm, off, 32));
    float cs = __expf(clsx - cm);
    #pragma unroll
    for (int off = 16; off >= 1; off >>= 1)
        cs += __shfl_xor(cs, off, 32);
    const float xt = __shfl(clsx, tg + (lane & 32));
    const float c = (cm + __logf(cs)) - xt;
    const float cls_tot = __shfl(c, 0) + __shfl(c, 32);

    // ---- bce on lanes 0-1 ----
    float bsum = 0.f, vsum = 0.f;
    if (lane < 2 && seq2) {
        const float te = (!data2) ? 1.f : 0.f;
        bsum = fmaxf(xe, 0.f) - xe * te + log1pf(__expf(-fabsf(xe)));
        vsum = 1.f;
    }
    bsum += __shfl_xor(bsum, 1);
    vsum += __shfl_xor(vsum, 1);

    if (lane == 0) {
        float* q = partials[blockIdx.x].v;
        *(float4*)q = make_float4(cls_tot, ptr_sum, ptr_cnt, bsum);
        q[4] = vsum;
    }
}

// Reduce 11008 partials (352 KB) -> 4 outputs. One block, 1024 threads.
__global__ __launch_bounds__(1024) void reduce_kernel(const Partial* __restrict__ partials,
                                                      float* __restrict__ out)
{
    __shared__ float sm[16][5];
    float c = 0.f, p = 0.f, n = 0.f, e = 0.f, v = 0.f;
    for (int i = threadIdx.x; i < NPART; i += 1024) {
        const float* q = partials[i].v;
        const float4 a = *(const float4*)q;
        c += a.x; p += a.y; n += a.z; e += a.w; v += q[4];
    }
    #pragma unroll
    for (int off = 32; off >= 1; off >>= 1) {
        c += __shfl_xor(c, off);
        p += __shfl_xor(p, off);
        n += __shfl_xor(n, off);
        e += __shfl_xor(e, off);
        v += __shfl_xor(v, off);
    }
    const int wv = threadIdx.x >> 6;
    if ((threadIdx.x & 63) == 0) {
        sm[wv][0] = c; sm[wv][1] = p; sm[wv][2] = n; sm[wv][3] = e; sm[wv][4] = v;
    }
    __syncthreads();
    if (threadIdx.x == 0) {
        float tc = 0.f, tp = 0.f, tn = 0.f, tb = 0.f, tv = 0.f;
        #pragma unroll
        for (int i = 0; i < 16; ++i) {
            tc += sm[i][0]; tp += sm[i][1]; tn += sm[i][2];
            tb += sm[i][3]; tv += sm[i][4];
        }
        const float cls_loss = tc / (float)ROWS;
        const float ptr_loss = (tn == 0.f) ? 0.f : tp / fmaxf(tn, 1.f);
        const float emp_loss = tb / fmaxf(tv, 1.f);
        out[0] = cls_loss + ptr_loss + emp_loss;
        out[1] = cls_loss;
        out[2] = ptr_loss;
        out[3] = emp_loss;
    }
}

extern "C" void kernel_launch(void* const* d_in, const int* in_sizes, int n_in,
                              void* d_out, int out_size, void* d_ws, size_t ws_size,
                              hipStream_t stream) {
    const float* tag_logits           = (const float*)d_in[0];
    const float* pointer_logits       = (const float*)d_in[1];
    const float* empty_pointer_logits = (const float*)d_in[2];
    const int*   tag_targets          = (const int*)d_in[3];
    const int*   box_indices          = (const int*)d_in[4];
    const int*   data_tag_mask        = (const int*)d_in[5];
    const int*   attention_mask       = (const int*)d_in[6];
    float* out = (float*)d_out;
    Partial* partials = (Partial*)d_ws;

    fused_kernel<<<NPART, 64, 0, stream>>>(tag_logits, pointer_logits,
                                           empty_pointer_logits, tag_targets,
                                           box_indices, data_tag_mask,
                                           attention_mask, partials);
    reduce_kernel<<<1, 1024, 0, stream>>>(partials, out);
}

// Round 7
// 112.863 us; speedup vs baseline: 1.3056x; 1.0099x over previous
//
#include <hip/hip_runtime.h>
#include <hip/hip_bf16.h>
#include <math.h>

// Problem constants: B=32, L=688, M=4, C=32
#define BB 32
#define LL 688
#define MM 4
#define CC 32
#define ROWS (BB * LL)        // 22016
#define RPW 4                 // rows per wave
#define NPART (ROWS / RPW)    // 5504 one-wave blocks

struct Partial { float v[8]; };   // {cls, ptr, cnt, bce, vm, pad...} 32 B

__device__ __forceinline__ float max12(float4 x, float4 y, float4 z) {
    return fmaxf(fmaxf(fmaxf(fmaxf(x.x, x.y), fmaxf(x.z, x.w)),
                       fmaxf(fmaxf(y.x, y.y), fmaxf(y.z, y.w))),
                 fmaxf(fmaxf(z.x, z.y), fmaxf(z.z, z.w)));
}

__device__ __forceinline__ float msum12(float4 x, float4 y, float4 z,
                                        float4 f0, float4 f1, float4 f2, float m) {
    float s = 0.f;
    s = fmaf(f0.x, __expf(x.x - m), s);
    s = fmaf(f0.y, __expf(x.y - m), s);
    s = fmaf(f0.z, __expf(x.z - m), s);
    s = fmaf(f0.w, __expf(x.w - m), s);
    s = fmaf(f1.x, __expf(y.x - m), s);
    s = fmaf(f1.y, __expf(y.y - m), s);
    s = fmaf(f1.z, __expf(y.z - m), s);
    s = fmaf(f1.w, __expf(y.w - m), s);
    s = fmaf(f2.x, __expf(z.x - m), s);
    s = fmaf(f2.y, __expf(z.y - m), s);
    s = fmaf(f2.z, __expf(z.z - m), s);
    s = fmaf(f2.w, __expf(z.w - m), s);
    return s;
}

// One wave64 per 4 consecutive rows (688%4==0 -> same batch per wave).
// Fully independent 64-thread blocks: no LDS, no syncthreads, no atomics.
// All loads hoisted up front (~13KB in flight); 4 interleaved butterfly
// chains; 16-lane gather tail; wave writes one 32B partial.
__global__ __launch_bounds__(64) void fused_kernel(
    const float* __restrict__ tag_logits,
    const float* __restrict__ pl,
    const float* __restrict__ epl,
    const int* __restrict__ tag_targets,
    const int* __restrict__ box,
    const int* __restrict__ dtm,
    const int* __restrict__ am,
    Partial* __restrict__ partials)
{
    const int lane = threadIdx.x;
    const int row0 = blockIdx.x * RPW;
    const int bat  = row0 / LL;
    const int jcol0 = row0 - bat * LL;

    const int* mrow = dtm + bat * (2 * LL) + LL;   // seq_mask[bat, :]
    const int4* maskp = (const int4*)mrow;
    const bool has2 = (lane < 44);                 // 172 - 128

    // ---- issue ALL independent loads up front ----
    const int4 mi0 = maskp[lane];
    const int4 mi1 = maskp[lane + 64];
    const int4 mi2 = has2 ? maskp[lane + 128] : make_int4(0, 0, 0, 0);

    const float4 NEGV = make_float4(-INFINITY, -INFINITY, -INFINITY, -INFINITY);
    const float4* rp0 = (const float4*)(pl + (size_t)(row0 + 0) * LL);
    const float4* rp1 = (const float4*)(pl + (size_t)(row0 + 1) * LL);
    const float4* rp2 = (const float4*)(pl + (size_t)(row0 + 2) * LL);
    const float4* rp3 = (const float4*)(pl + (size_t)(row0 + 3) * LL);
    const float4 a0 = rp0[lane], a1 = rp0[lane + 64], a2 = has2 ? rp0[lane + 128] : NEGV;
    const float4 c0 = rp1[lane], c1 = rp1[lane + 64], c2 = has2 ? rp1[lane + 128] : NEGV;
    const float4 d0 = rp2[lane], d1 = rp2[lane + 64], d2 = has2 ? rp2[lane + 128] : NEGV;
    const float4 e0 = rp3[lane], e1 = rp3[lane + 64], e2 = has2 ? rp3[lane + 128] : NEGV;

    // gather chain (lanes 0-15): box -> mask -> logit
    const int r  = (lane & 15) >> 2;     // row within quad
    const int mi = lane & 3;             // box slot
    const int rowr = row0 + r;
    int t = -1, tmask = 0;
    float xj = 0.f;
    if (lane < 16) {
        t = box[(size_t)rowr * MM + mi];
        const int tcl = t < 0 ? 0 : (t > LL - 1 ? LL - 1 : t);
        tmask = mrow[tcl];
        xj = pl[(size_t)rowr * LL + tcl];
    }

    // cls loads: half-wave per row, 2 passes
    const int half = lane >> 5;
    const int cid  = lane & 31;
    const float clsx0 = tag_logits[(size_t)(row0 + half) * CC + cid];
    const float clsx1 = tag_logits[(size_t)(row0 + 2 + half) * CC + cid];
    const int tg0 = tag_targets[row0 + half];
    const int tg1 = tag_targets[row0 + 2 + half];

    // bce loads (lanes 0-3)
    int seq2 = 0, data2 = 0;
    float xe = 0.f;
    if (lane < 4) {
        const int offb = bat * (2 * LL) + LL + (jcol0 + lane);
        seq2  = am[offb];
        data2 = dtm[offb];
        xe    = epl[row0 + lane];
    }

    // ---- mask -> float ----
    const float4 f0 = make_float4(mi0.x ? 1.f : 0.f, mi0.y ? 1.f : 0.f,
                                  mi0.z ? 1.f : 0.f, mi0.w ? 1.f : 0.f);
    const float4 f1 = make_float4(mi1.x ? 1.f : 0.f, mi1.y ? 1.f : 0.f,
                                  mi1.z ? 1.f : 0.f, mi1.w ? 1.f : 0.f);
    const float4 f2 = make_float4(mi2.x ? 1.f : 0.f, mi2.y ? 1.f : 0.f,
                                  mi2.z ? 1.f : 0.f, mi2.w ? 1.f : 0.f);

    // ---- 4 interleaved wave reductions: max then masked exp-sum ----
    float pm0 = max12(a0, a1, a2);
    float pm1 = max12(c0, c1, c2);
    float pm2 = max12(d0, d1, d2);
    float pm3 = max12(e0, e1, e2);
    #pragma unroll
    for (int off = 32; off >= 1; off >>= 1) {
        pm0 = fmaxf(pm0, __shfl_xor(pm0, off));
        pm1 = fmaxf(pm1, __shfl_xor(pm1, off));
        pm2 = fmaxf(pm2, __shfl_xor(pm2, off));
        pm3 = fmaxf(pm3, __shfl_xor(pm3, off));
    }
    float ps0 = msum12(a0, a1, a2, f0, f1, f2, pm0);
    float ps1 = msum12(c0, c1, c2, f0, f1, f2, pm1);
    float ps2 = msum12(d0, d1, d2, f0, f1, f2, pm2);
    float ps3 = msum12(e0, e1, e2, f0, f1, f2, pm3);
    #pragma unroll
    for (int off = 32; off >= 1; off >>= 1) {
        ps0 += __shfl_xor(ps0, off);
        ps1 += __shfl_xor(ps1, off);
        ps2 += __shfl_xor(ps2, off);
        ps3 += __shfl_xor(ps3, off);
    }

    // ---- pointer tail: dedupe + loss on lanes 0-15 ----
    const int ta  = __shfl(t, (lane & ~3));
    const int tb  = __shfl(t, (lane & ~3) + 1);
    const int tc2 = __shfl(t, (lane & ~3) + 2);
    float contrib = 0.f, ccnt = 0.f;
    if (lane < 16) {
        const bool dup = (mi > 0 && t == ta) || (mi > 1 && t == tb) || (mi > 2 && t == tc2);
        if (t >= 0 && !dup && tmask) {
            const float mxr = (r == 0) ? pm0 : (r == 1) ? pm1 : (r == 2) ? pm2 : pm3;
            const float dnr = ((r == 0) ? ps0 : (r == 1) ? ps1 : (r == 2) ? ps2 : ps3) + 1e-10f;
            const float p = __expf(xj - mxr) / dnr + 1e-10f;
            const float v = -__logf(p);
            contrib = v;
            ccnt = (v != 0.0f) ? 1.f : 0.f;
        }
    }
    contrib += __shfl_xor(contrib, 1); contrib += __shfl_xor(contrib, 2);
    ccnt    += __shfl_xor(ccnt, 1);    ccnt    += __shfl_xor(ccnt, 2);
    const float ptr_sum = __shfl(contrib, 0) + __shfl(contrib, 4) +
                          __shfl(contrib, 8) + __shfl(contrib, 12);
    const float ptr_cnt = __shfl(ccnt, 0) + __shfl(ccnt, 4) +
                          __shfl(ccnt, 8) + __shfl(ccnt, 12);

    // ---- cls: 2 passes, half-wave per row ----
    float cls_tot = 0.f;
    {
        float cm = clsx0;
        #pragma unroll
        for (int off = 16; off >= 1; off >>= 1)
            cm = fmaxf(cm, __shfl_xor(cm, off, 32));
        float cs = __expf(clsx0 - cm);
        #pragma unroll
        for (int off = 16; off >= 1; off >>= 1)
            cs += __shfl_xor(cs, off, 32);
        const float xt = __shfl(clsx0, tg0 + (lane & 32));
        const float c = (cm + __logf(cs)) - xt;
        cls_tot += __shfl(c, 0) + __shfl(c, 32);
    }
    {
        float cm = clsx1;
        #pragma unroll
        for (int off = 16; off >= 1; off >>= 1)
            cm = fmaxf(cm, __shfl_xor(cm, off, 32));
        float cs = __expf(clsx1 - cm);
        #pragma unroll
        for (int off = 16; off >= 1; off >>= 1)
            cs += __shfl_xor(cs, off, 32);
        const float xt = __shfl(clsx1, tg1 + (lane & 32));
        const float c = (cm + __logf(cs)) - xt;
        cls_tot += __shfl(c, 0) + __shfl(c, 32);
    }

    // ---- bce on lanes 0-3 ----
    float bsum = 0.f, vsum = 0.f;
    if (lane < 4 && seq2) {
        const float te = (!data2) ? 1.f : 0.f;
        bsum = fmaxf(xe, 0.f) - xe * te + log1pf(__expf(-fabsf(xe)));
        vsum = 1.f;
    }
    bsum += __shfl_xor(bsum, 1); bsum += __shfl_xor(bsum, 2);
    vsum += __shfl_xor(vsum, 1); vsum += __shfl_xor(vsum, 2);

    if (lane == 0) {
        float* q = partials[blockIdx.x].v;
        *(float4*)q = make_float4(cls_tot, ptr_sum, ptr_cnt, bsum);
        q[4] = vsum;
    }
}

// Reduce 5504 partials (176 KB) -> 4 outputs. One block, 1024 threads.
__global__ __launch_bounds__(1024) void reduce_kernel(const Partial* __restrict__ partials,
                                                      float* __restrict__ out)
{
    __shared__ float sm[16][5];
    float c = 0.f, p = 0.f, n = 0.f, e = 0.f, v = 0.f;
    for (int i = threadIdx.x; i < NPART; i += 1024) {
        const float* q = partials[i].v;
        const float4 a = *(const float4*)q;
        c += a.x; p += a.y; n += a.z; e += a.w; v += q[4];
    }
    #pragma unroll
    for (int off = 32; off >= 1; off >>= 1) {
        c += __shfl_xor(c, off);
        p += __shfl_xor(p, off);
        n += __shfl_xor(n, off);
        e += __shfl_xor(e, off);
        v += __shfl_xor(v, off);
    }
    const int wv = threadIdx.x >> 6;
    if ((threadIdx.x & 63) == 0) {
        sm[wv][0] = c; sm[wv][1] = p; sm[wv][2] = n; sm[wv][3] = e; sm[wv][4] = v;
    }
    __syncthreads();
    if (threadIdx.x == 0) {
        float tc = 0.f, tp = 0.f, tn = 0.f, tb = 0.f, tv = 0.f;
        #pragma unroll
        for (int i = 0; i < 16; ++i) {
            tc += sm[i][0]; tp += sm[i][1]; tn += sm[i][2];
            tb += sm[i][3]; tv += sm[i][4];
        }
        const float cls_loss = tc / (float)ROWS;
        const float ptr_loss = (tn == 0.f) ? 0.f : tp / fmaxf(tn, 1.f);
        const float emp_loss = tb / fmaxf(tv, 1.f);
        out[0] = cls_loss + ptr_loss + emp_loss;
        out[1] = cls_loss;
        out[2] = ptr_loss;
        out[3] = emp_loss;
    }
}

extern "C" void kernel_launch(void* const* d_in, const int* in_sizes, int n_in,
                              void* d_out, int out_size, void* d_ws, size_t ws_size,
                              hipStream_t stream) {
    const float* tag_logits           = (const float*)d_in[0];
    const float* pointer_logits       = (const float*)d_in[1];
    const float* empty_pointer_logits = (const float*)d_in[2];
    const int*   tag_targets          = (const int*)d_in[3];
    const int*   box_indices          = (const int*)d_in[4];
    const int*   data_tag_mask        = (const int*)d_in[5];
    const int*   attention_mask       = (const int*)d_in[6];
    float* out = (float*)d_out;
    Partial* partials = (Partial*)d_ws;

    fused_kernel<<<NPART, 64, 0, stream>>>(tag_logits, pointer_logits,
                                           empty_pointer_logits, tag_targets,
                                           box_indices, data_tag_mask,
                                           attention_mask, partials);
    reduce_kernel<<<1, 1024, 0, stream>>>(partials, out);
}